// Round 2
// baseline (490.339 us; speedup 1.0000x reference)
//
#include <hip/hip_runtime.h>

#define NN 100000
#define NE 1600000

#define FMA4(A_, S_, W_)                                          \
  A_.x = fmaf(S_, W_.x, A_.x); A_.y = fmaf(S_, W_.y, A_.y);       \
  A_.z = fmaf(S_, W_.z, A_.z); A_.w = fmaf(S_, W_.w, A_.w);

// h[n][0:64] = feat@W_l row, h[n][64:128] = feat@W_r row
__global__ __launch_bounds__(256) void gemm_dual(const float* __restrict__ feat,
                                                 const float* __restrict__ wl,
                                                 const float* __restrict__ wr,
                                                 float* __restrict__ h) {
  __shared__ float ldsW[128][128];   // 64 KB: combined [k][c], c<64 -> W_l, c>=64 -> W_r
  __shared__ float ldsF[32][128];    // 16 KB feature tile
  const int tid = threadIdx.x;

  for (int idx = tid; idx < 128 * 64; idx += 256) {
    int k = idx >> 6, c = idx & 63;
    ldsW[k][c]      = wl[idx];
    ldsW[k][c + 64] = wr[idx];
  }

  const int row0 = blockIdx.x * 32;
  for (int idx = tid; idx < 32 * 32; idx += 256) {   // 32 rows x 32 float4
    int r = idx >> 5, c4 = idx & 31;
    int gr = row0 + r;
    float4 v = make_float4(0.f, 0.f, 0.f, 0.f);
    if (gr < NN) v = reinterpret_cast<const float4*>(feat)[(size_t)gr * 32 + c4];
    *reinterpret_cast<float4*>(&ldsF[r][c4 * 4]) = v;
  }
  __syncthreads();

  const int r0 = (tid >> 5) * 4;   // 8 row groups x 4 rows = 32 rows
  const int c0 = (tid & 31) * 4;   // 32 col groups x 4 cols = 128 cols
  float4 acc[4];
  acc[0] = acc[1] = acc[2] = acc[3] = make_float4(0.f, 0.f, 0.f, 0.f);

  for (int k = 0; k < 128; k += 4) {
    float4 w0 = *reinterpret_cast<const float4*>(&ldsW[k    ][c0]);
    float4 w1 = *reinterpret_cast<const float4*>(&ldsW[k + 1][c0]);
    float4 w2 = *reinterpret_cast<const float4*>(&ldsW[k + 2][c0]);
    float4 w3 = *reinterpret_cast<const float4*>(&ldsW[k + 3][c0]);
#pragma unroll
    for (int i = 0; i < 4; ++i) {
      float4 f = *reinterpret_cast<const float4*>(&ldsF[r0 + i][k]);
      FMA4(acc[i], f.x, w0);
      FMA4(acc[i], f.y, w1);
      FMA4(acc[i], f.z, w2);
      FMA4(acc[i], f.w, w3);
    }
  }

#pragma unroll
  for (int i = 0; i < 4; ++i) {
    int gr = row0 + r0 + i;
    if (gr < NN)
      *reinterpret_cast<float4*>(&h[(size_t)gr * 128 + c0]) = acc[i];
  }
}

__global__ void hist_k(const int* __restrict__ tgt, int* __restrict__ cnt) {
  int e = blockIdx.x * 256 + threadIdx.x;
  if (e < NE) atomicAdd(&cnt[tgt[e]], 1);
}

// Block-level scan: 49 blocks x 2048 elements
__global__ __launch_bounds__(256) void scan1_k(const int* __restrict__ cnt,
                                               int* __restrict__ start,
                                               int* __restrict__ bsums) {
  __shared__ int sd[256];
  const int tid = threadIdx.x;
  const int base = blockIdx.x * 2048;
  int v[8];
  int s = 0;
#pragma unroll
  for (int i = 0; i < 8; ++i) {
    int idx = base + tid * 8 + i;
    v[i] = (idx < NN) ? cnt[idx] : 0;
    s += v[i];
  }
  sd[tid] = s;
  __syncthreads();
  for (int off = 1; off < 256; off <<= 1) {
    int t = (tid >= off) ? sd[tid - off] : 0;
    __syncthreads();
    sd[tid] += t;
    __syncthreads();
  }
  int run = sd[tid] - s;   // exclusive prefix of this thread within block
#pragma unroll
  for (int i = 0; i < 8; ++i) {
    int idx = base + tid * 8 + i;
    if (idx < NN) start[idx] = run;
    run += v[i];
  }
  if (tid == 255) bsums[blockIdx.x] = sd[255];
}

__global__ void scan2_k(int* __restrict__ bsums, int nb) {
  if (threadIdx.x == 0) {
    int acc = 0;
    for (int i = 0; i < nb; ++i) { int t = bsums[i]; bsums[i] = acc; acc += t; }
  }
}

__global__ void scan3_k(int* __restrict__ start, const int* __restrict__ bsums) {
  int i = blockIdx.x * 256 + threadIdx.x;
  if (i < NN) start[i] += bsums[i >> 11];
  if (i == 0) start[NN] = NE;
}

__global__ void scatter_k(const int* __restrict__ edge,
                          const int* __restrict__ start,
                          int* __restrict__ cursor,
                          int* __restrict__ ssrc) {
  int e = blockIdx.x * 256 + threadIdx.x;
  if (e < NE) {
    int t = edge[NE + e];                      // tgt row
    int pos = start[t] + atomicAdd(&cursor[t], 1);
    ssrc[pos] = edge[e];                       // src row
  }
}

// One wave per node: register-resident online softmax + aggregation. No float atomics.
__global__ __launch_bounds__(256) void node_k(const float* __restrict__ h,
                                              const int* __restrict__ ssrc,
                                              const int* __restrict__ start,
                                              const float* __restrict__ att,
                                              const float* __restrict__ bias,
                                              float* __restrict__ out) {
  const int lane = threadIdx.x & 63;
  const int n = blockIdx.x * 4 + (threadIdx.x >> 6);

  const float xi = h[(size_t)n * 128 + lane];   // h_l[n] fragment (lane = h*16+f)
  const float a  = att[lane];
  const int s = start[n];
  const int e = start[n + 1];

  float den = 0.f;
  float acc = 0.f;
  for (int i = s; i < e; ++i) {
    int src = ssrc[i];
    float xj = h[(size_t)src * 128 + 64 + lane];   // h_r[src] fragment
    float z = xi + xj;
    z = (z >= 0.f) ? z : 0.2f * z;                 // leaky_relu
    float t = z * a;
    t += __shfl_xor(t, 1);                         // 16-lane (per-head) reduce
    t += __shfl_xor(t, 2);
    t += __shfl_xor(t, 4);
    t += __shfl_xor(t, 8);
    float ex = __expf(t);                          // no max-shift needed (|score| << 88)
    den += ex;
    acc = fmaf(ex, xj, acc);
  }
  float r = (e > s) ? acc / den : 0.f;             // deg==0 -> segment_sum of nothing
  out[(size_t)n * 64 + lane] = r + bias[lane];
}

extern "C" void kernel_launch(void* const* d_in, const int* in_sizes, int n_in,
                              void* d_out, int out_size, void* d_ws, size_t ws_size,
                              hipStream_t stream) {
  const float* feat = (const float*)d_in[0];
  const int*   edge = (const int*)d_in[1];
  const float* wl   = (const float*)d_in[2];
  const float* wr   = (const float*)d_in[3];
  const float* att  = (const float*)d_in[4];
  const float* bias = (const float*)d_in[5];
  float* out = (float*)d_out;

  // workspace layout (~58.9 MB)
  float* h     = (float*)d_ws;                 // NN*128 f32
  int* ssrc    = (int*)(h + (size_t)NN * 128); // NE
  int* cnt     = ssrc + NE;                    // NN
  int* cursor  = cnt + NN;                     // NN
  int* start   = cursor + NN;                  // NN+1
  int* bsums   = start + NN + 1;               // 49

  (void)hipMemsetAsync(cnt, 0, 2 * NN * sizeof(int), stream);  // cnt + cursor

  gemm_dual<<<(NN + 31) / 32, 256, 0, stream>>>(feat, wl, wr, h);
  hist_k<<<(NE + 255) / 256, 256, 0, stream>>>(edge + NE, cnt);
  scan1_k<<<49, 256, 0, stream>>>(cnt, start, bsums);
  scan2_k<<<1, 64, 0, stream>>>(bsums, 49);
  scan3_k<<<(NN + 255) / 256, 256, 0, stream>>>(start, bsums);
  scatter_k<<<(NE + 255) / 256, 256, 0, stream>>>(edge, start, cursor, ssrc);
  node_k<<<NN / 4, 256, 0, stream>>>(h, ssrc, start, att, bias, out);
}

// Round 3
// 396.467 us; speedup vs baseline: 1.2368x; 1.2368x over previous
//
#include <hip/hip_runtime.h>

#define NN 100000
#define NE 1600000

#define FMA4(A_, S_, W_)                                          \
  A_.x = fmaf(S_, W_.x, A_.x); A_.y = fmaf(S_, W_.y, A_.y);       \
  A_.z = fmaf(S_, W_.z, A_.z); A_.w = fmaf(S_, W_.w, A_.w);

// h[n][0:64] = feat@W_l row, h[n][64:128] = feat@W_r row
__global__ __launch_bounds__(256) void gemm_dual(const float* __restrict__ feat,
                                                 const float* __restrict__ wl,
                                                 const float* __restrict__ wr,
                                                 float* __restrict__ h) {
  __shared__ float ldsW[128][128];   // 64 KB: combined [k][c], c<64 -> W_l, c>=64 -> W_r
  __shared__ float ldsF[32][128];    // 16 KB feature tile
  const int tid = threadIdx.x;

  for (int idx = tid; idx < 2048; idx += 256) {   // 2048 float4 per W
    int k = idx >> 4, c4 = (idx & 15) * 4;
    float4 vl = reinterpret_cast<const float4*>(wl)[idx];
    float4 vr = reinterpret_cast<const float4*>(wr)[idx];
    *reinterpret_cast<float4*>(&ldsW[k][c4])      = vl;
    *reinterpret_cast<float4*>(&ldsW[k][c4 + 64]) = vr;
  }

  const int row0 = blockIdx.x * 32;
  for (int idx = tid; idx < 32 * 32; idx += 256) {   // 32 rows x 32 float4
    int r = idx >> 5, c4 = idx & 31;
    int gr = row0 + r;
    float4 v = make_float4(0.f, 0.f, 0.f, 0.f);
    if (gr < NN) v = reinterpret_cast<const float4*>(feat)[(size_t)gr * 32 + c4];
    *reinterpret_cast<float4*>(&ldsF[r][c4 * 4]) = v;
  }
  __syncthreads();

  const int r0 = (tid >> 5) * 4;   // 8 row groups x 4 rows = 32 rows
  const int c0 = (tid & 31) * 4;   // 32 col groups x 4 cols = 128 cols
  float4 acc[4];
  acc[0] = acc[1] = acc[2] = acc[3] = make_float4(0.f, 0.f, 0.f, 0.f);

  for (int k = 0; k < 128; k += 4) {
    float4 w0 = *reinterpret_cast<const float4*>(&ldsW[k    ][c0]);
    float4 w1 = *reinterpret_cast<const float4*>(&ldsW[k + 1][c0]);
    float4 w2 = *reinterpret_cast<const float4*>(&ldsW[k + 2][c0]);
    float4 w3 = *reinterpret_cast<const float4*>(&ldsW[k + 3][c0]);
#pragma unroll
    for (int i = 0; i < 4; ++i) {
      float4 f = *reinterpret_cast<const float4*>(&ldsF[r0 + i][k]);
      FMA4(acc[i], f.x, w0);
      FMA4(acc[i], f.y, w1);
      FMA4(acc[i], f.z, w2);
      FMA4(acc[i], f.w, w3);
    }
  }

#pragma unroll
  for (int i = 0; i < 4; ++i) {
    int gr = row0 + r0 + i;
    if (gr < NN)
      *reinterpret_cast<float4*>(&h[(size_t)gr * 128 + c0]) = acc[i];
  }
}

__global__ void hist_k(const int* __restrict__ tgt, int* __restrict__ cnt) {
  int e = blockIdx.x * 256 + threadIdx.x;
  if (e < NE) atomicAdd(&cnt[tgt[e]], 1);
}

// Block-level scan: 49 blocks x 2048 elements
__global__ __launch_bounds__(256) void scan1_k(const int* __restrict__ cnt,
                                               int* __restrict__ start,
                                               int* __restrict__ bsums) {
  __shared__ int sd[256];
  const int tid = threadIdx.x;
  const int base = blockIdx.x * 2048;
  int v[8];
  int s = 0;
#pragma unroll
  for (int i = 0; i < 8; ++i) {
    int idx = base + tid * 8 + i;
    v[i] = (idx < NN) ? cnt[idx] : 0;
    s += v[i];
  }
  sd[tid] = s;
  __syncthreads();
  for (int off = 1; off < 256; off <<= 1) {
    int t = (tid >= off) ? sd[tid - off] : 0;
    __syncthreads();
    sd[tid] += t;
    __syncthreads();
  }
  int run = sd[tid] - s;   // exclusive prefix of this thread within block
#pragma unroll
  for (int i = 0; i < 8; ++i) {
    int idx = base + tid * 8 + i;
    if (idx < NN) start[idx] = run;
    run += v[i];
  }
  if (tid == 255) bsums[blockIdx.x] = sd[255];
}

__global__ void scan2_k(int* __restrict__ bsums, int nb) {
  if (threadIdx.x == 0) {
    int acc = 0;
    for (int i = 0; i < nb; ++i) { int t = bsums[i]; bsums[i] = acc; acc += t; }
  }
}

__global__ void scan3_k(int* __restrict__ start, const int* __restrict__ bsums) {
  int i = blockIdx.x * 256 + threadIdx.x;
  if (i < NN) start[i] += bsums[i >> 11];
  if (i == 0) start[NN] = NE;
}

__global__ void scatter_k(const int* __restrict__ edge,
                          const int* __restrict__ start,
                          int* __restrict__ cursor,
                          int* __restrict__ ssrc) {
  int e = blockIdx.x * 256 + threadIdx.x;
  if (e < NE) {
    int t = edge[NE + e];                      // tgt row
    int pos = start[t] + atomicAdd(&cursor[t], 1);
    ssrc[pos] = edge[e];                       // src row
  }
}

__device__ __forceinline__ float edge_exp(float xi, float xj, float a) {
  float z = xi + xj;
  z = fmaxf(z, 0.2f * z);                      // leaky_relu
  float t = z * a;
  t += __shfl_xor(t, 1);                       // 16-lane (per-head) reduce
  t += __shfl_xor(t, 2);
  t += __shfl_xor(t, 4);
  t += __shfl_xor(t, 8);
  return __expf(t);                            // no max-shift needed (|score| << 88)
}

// One wave per node, edge loop unrolled x4 for MLP. No float atomics.
__global__ __launch_bounds__(256) void node_k(const float* __restrict__ h,
                                              const int* __restrict__ ssrc,
                                              const int* __restrict__ start,
                                              const float* __restrict__ att,
                                              const float* __restrict__ bias,
                                              float* __restrict__ out) {
  const int lane = threadIdx.x & 63;
  const int n = blockIdx.x * 4 + (threadIdx.x >> 6);

  const float xi = h[(size_t)n * 128 + lane];   // h_l[n] fragment (lane = h*16+f)
  const float a  = att[lane];
  const int s = start[n];
  const int e = start[n + 1];
  const float* __restrict__ hr = h + 64 + lane; // h_r base for this lane

  float den = 0.f;
  float acc = 0.f;
  int i = s;
  for (; i + 4 <= e; i += 4) {
    int j0 = ssrc[i + 0];
    int j1 = ssrc[i + 1];
    int j2 = ssrc[i + 2];
    int j3 = ssrc[i + 3];
    float x0 = hr[(size_t)j0 * 128];            // 4 independent gathers in flight
    float x1 = hr[(size_t)j1 * 128];
    float x2 = hr[(size_t)j2 * 128];
    float x3 = hr[(size_t)j3 * 128];
    float e0 = edge_exp(xi, x0, a);             // 4 interleaved shfl/exp chains
    float e1 = edge_exp(xi, x1, a);
    float e2 = edge_exp(xi, x2, a);
    float e3 = edge_exp(xi, x3, a);
    den += (e0 + e1) + (e2 + e3);
    acc = fmaf(e0, x0, acc);
    acc = fmaf(e1, x1, acc);
    acc = fmaf(e2, x2, acc);
    acc = fmaf(e3, x3, acc);
  }
  for (; i < e; ++i) {
    int j = ssrc[i];
    float xj = hr[(size_t)j * 128];
    float ex = edge_exp(xi, xj, a);
    den += ex;
    acc = fmaf(ex, xj, acc);
  }
  float r = (e > s) ? acc / den : 0.f;          // deg==0 -> segment_sum of nothing
  out[(size_t)n * 64 + lane] = r + bias[lane];
}

extern "C" void kernel_launch(void* const* d_in, const int* in_sizes, int n_in,
                              void* d_out, int out_size, void* d_ws, size_t ws_size,
                              hipStream_t stream) {
  const float* feat = (const float*)d_in[0];
  const int*   edge = (const int*)d_in[1];
  const float* wl   = (const float*)d_in[2];
  const float* wr   = (const float*)d_in[3];
  const float* att  = (const float*)d_in[4];
  const float* bias = (const float*)d_in[5];
  float* out = (float*)d_out;

  // workspace layout (~58.9 MB)
  float* h     = (float*)d_ws;                 // NN*128 f32
  int* ssrc    = (int*)(h + (size_t)NN * 128); // NE
  int* cnt     = ssrc + NE;                    // NN
  int* cursor  = cnt + NN;                     // NN
  int* start   = cursor + NN;                  // NN+1
  int* bsums   = start + NN + 1;               // 49

  (void)hipMemsetAsync(cnt, 0, 2 * NN * sizeof(int), stream);  // cnt + cursor

  gemm_dual<<<(NN + 31) / 32, 256, 0, stream>>>(feat, wl, wr, h);
  hist_k<<<(NE + 255) / 256, 256, 0, stream>>>(edge + NE, cnt);
  scan1_k<<<49, 256, 0, stream>>>(cnt, start, bsums);
  scan2_k<<<1, 64, 0, stream>>>(bsums, 49);
  scan3_k<<<(NN + 255) / 256, 256, 0, stream>>>(start, bsums);
  scatter_k<<<(NE + 255) / 256, 256, 0, stream>>>(edge, start, cursor, ssrc);
  node_k<<<NN / 4, 256, 0, stream>>>(h, ssrc, start, att, bias, out);
}

// Round 4
// 381.453 us; speedup vs baseline: 1.2855x; 1.0394x over previous
//
#include <hip/hip_runtime.h>

#define NN 100000
#define NE 1600000

#define FMA4(A_, S_, W_)                                          \
  A_.x = fmaf(S_, W_.x, A_.x); A_.y = fmaf(S_, W_.y, A_.y);       \
  A_.z = fmaf(S_, W_.z, A_.z); A_.w = fmaf(S_, W_.w, A_.w);

// h[n][0:64] = feat@W_l row, h[n][64:128] = feat@W_r row
__global__ __launch_bounds__(256) void gemm_dual(const float* __restrict__ feat,
                                                 const float* __restrict__ wl,
                                                 const float* __restrict__ wr,
                                                 float* __restrict__ h) {
  __shared__ float ldsW[128][128];   // 64 KB: combined [k][c], c<64 -> W_l, c>=64 -> W_r
  __shared__ float ldsF[32][128];    // 16 KB feature tile
  const int tid = threadIdx.x;

  for (int idx = tid; idx < 2048; idx += 256) {   // 2048 float4 per W
    int k = idx >> 4, c4 = (idx & 15) * 4;
    float4 vl = reinterpret_cast<const float4*>(wl)[idx];
    float4 vr = reinterpret_cast<const float4*>(wr)[idx];
    *reinterpret_cast<float4*>(&ldsW[k][c4])      = vl;
    *reinterpret_cast<float4*>(&ldsW[k][c4 + 64]) = vr;
  }

  const int row0 = blockIdx.x * 32;
  for (int idx = tid; idx < 32 * 32; idx += 256) {   // 32 rows x 32 float4
    int r = idx >> 5, c4 = idx & 31;
    int gr = row0 + r;
    float4 v = make_float4(0.f, 0.f, 0.f, 0.f);
    if (gr < NN) v = reinterpret_cast<const float4*>(feat)[(size_t)gr * 32 + c4];
    *reinterpret_cast<float4*>(&ldsF[r][c4 * 4]) = v;
  }
  __syncthreads();

  const int r0 = (tid >> 5) * 4;   // 8 row groups x 4 rows = 32 rows
  const int c0 = (tid & 31) * 4;   // 32 col groups x 4 cols = 128 cols
  float4 acc[4];
  acc[0] = acc[1] = acc[2] = acc[3] = make_float4(0.f, 0.f, 0.f, 0.f);

  for (int k = 0; k < 128; k += 4) {
    float4 w0 = *reinterpret_cast<const float4*>(&ldsW[k    ][c0]);
    float4 w1 = *reinterpret_cast<const float4*>(&ldsW[k + 1][c0]);
    float4 w2 = *reinterpret_cast<const float4*>(&ldsW[k + 2][c0]);
    float4 w3 = *reinterpret_cast<const float4*>(&ldsW[k + 3][c0]);
#pragma unroll
    for (int i = 0; i < 4; ++i) {
      float4 f = *reinterpret_cast<const float4*>(&ldsF[r0 + i][k]);
      FMA4(acc[i], f.x, w0);
      FMA4(acc[i], f.y, w1);
      FMA4(acc[i], f.z, w2);
      FMA4(acc[i], f.w, w3);
    }
  }

#pragma unroll
  for (int i = 0; i < 4; ++i) {
    int gr = row0 + r0 + i;
    if (gr < NN)
      *reinterpret_cast<float4*>(&h[(size_t)gr * 128 + c0]) = acc[i];
  }
}

__global__ void hist_k(const int* __restrict__ tgt, int* __restrict__ cnt) {
  int e = blockIdx.x * 256 + threadIdx.x;
  if (e < NE) atomicAdd(&cnt[tgt[e]], 1);
}

// Block-level scan: 49 blocks x 2048 elements
__global__ __launch_bounds__(256) void scan1_k(const int* __restrict__ cnt,
                                               int* __restrict__ start,
                                               int* __restrict__ bsums) {
  __shared__ int sd[256];
  const int tid = threadIdx.x;
  const int base = blockIdx.x * 2048;
  int v[8];
  int s = 0;
#pragma unroll
  for (int i = 0; i < 8; ++i) {
    int idx = base + tid * 8 + i;
    v[i] = (idx < NN) ? cnt[idx] : 0;
    s += v[i];
  }
  sd[tid] = s;
  __syncthreads();
  for (int off = 1; off < 256; off <<= 1) {
    int t = (tid >= off) ? sd[tid - off] : 0;
    __syncthreads();
    sd[tid] += t;
    __syncthreads();
  }
  int run = sd[tid] - s;   // exclusive prefix of this thread within block
#pragma unroll
  for (int i = 0; i < 8; ++i) {
    int idx = base + tid * 8 + i;
    if (idx < NN) start[idx] = run;
    run += v[i];
  }
  if (tid == 255) bsums[blockIdx.x] = sd[255];
}

// 64-lane shfl scan over <=64 block sums (replaces the serial 1-thread loop)
__global__ void scan2_k(int* __restrict__ bsums, int nb) {
  int lane = threadIdx.x;          // 64 threads
  int v = (lane < nb) ? bsums[lane] : 0;
  int orig = v;
  for (int off = 1; off < 64; off <<= 1) {
    int t = __shfl_up(v, off);
    if (lane >= off) v += t;
  }
  if (lane < nb) bsums[lane] = v - orig;   // exclusive prefix
}

__global__ void scan3_k(int* __restrict__ start, const int* __restrict__ bsums) {
  int i = blockIdx.x * 256 + threadIdx.x;
  if (i < NN) start[i] += bsums[i >> 11];
  if (i == 0) start[NN] = NE;
}

__global__ void scatter_k(const int* __restrict__ edge,
                          const int* __restrict__ start,
                          int* __restrict__ cursor,
                          int* __restrict__ ssrc) {
  int e = blockIdx.x * 256 + threadIdx.x;
  if (e < NE) {
    int t = edge[NE + e];                      // tgt row
    int pos = start[t] + atomicAdd(&cursor[t], 1);
    ssrc[pos] = edge[e];                       // src row
  }
}

// One wave per node; 16 lanes per edge (4 heads x float4), 4 edges per wave-step,
// hand-unrolled x2 (8 edges in flight). No float atomics, masked tail.
__global__ __launch_bounds__(256) void node_k(const float* __restrict__ h,
                                              const int* __restrict__ ssrc,
                                              const int* __restrict__ start,
                                              const float* __restrict__ att,
                                              const float* __restrict__ bias,
                                              float* __restrict__ out) {
  const int lane = threadIdx.x & 63;
  const int n  = blockIdx.x * 4 + (threadIdx.x >> 6);
  const int g  = lane >> 4;          // edge slot 0..3
  const int fo = (lane & 15) * 4;    // (head,feature-quad) offset within 64

  const float4 xi = *reinterpret_cast<const float4*>(h + (size_t)n * 128 + fo);
  const float4 a  = *reinterpret_cast<const float4*>(att + fo);
  const int s = start[n];
  const int e = start[n + 1];
  const float* __restrict__ hr = h + 64 + fo;   // h_r base for this lane

  float  den = 0.f;
  float4 acc = make_float4(0.f, 0.f, 0.f, 0.f);

  for (int i = s; i < e; i += 8) {
    int r0 = i + g, r1 = i + 4 + g;
    bool v0 = r0 < e, v1 = r1 < e;
    int j0 = ssrc[v0 ? r0 : s];
    int j1 = ssrc[v1 ? r1 : s];
    float4 x0 = *reinterpret_cast<const float4*>(hr + (size_t)j0 * 128);
    float4 x1 = *reinterpret_cast<const float4*>(hr + (size_t)j1 * 128);

    float4 z0, z1;
    z0.x = xi.x + x0.x; z0.y = xi.y + x0.y; z0.z = xi.z + x0.z; z0.w = xi.w + x0.w;
    z1.x = xi.x + x1.x; z1.y = xi.y + x1.y; z1.z = xi.z + x1.z; z1.w = xi.w + x1.w;
    z0.x = fmaxf(z0.x, 0.2f * z0.x); z0.y = fmaxf(z0.y, 0.2f * z0.y);
    z0.z = fmaxf(z0.z, 0.2f * z0.z); z0.w = fmaxf(z0.w, 0.2f * z0.w);
    z1.x = fmaxf(z1.x, 0.2f * z1.x); z1.y = fmaxf(z1.y, 0.2f * z1.y);
    z1.z = fmaxf(z1.z, 0.2f * z1.z); z1.w = fmaxf(z1.w, 0.2f * z1.w);

    float t0 = z0.x * a.x; t0 = fmaf(z0.y, a.y, t0);
    t0 = fmaf(z0.z, a.z, t0); t0 = fmaf(z0.w, a.w, t0);
    float t1 = z1.x * a.x; t1 = fmaf(z1.y, a.y, t1);
    t1 = fmaf(z1.z, a.z, t1); t1 = fmaf(z1.w, a.w, t1);

    t0 += __shfl_xor(t0, 1); t0 += __shfl_xor(t0, 2);   // per-head dot (4 lanes)
    t1 += __shfl_xor(t1, 1); t1 += __shfl_xor(t1, 2);

    float e0 = v0 ? __expf(t0) : 0.f;   // no max-shift needed (|score| << 88)
    float e1 = v1 ? __expf(t1) : 0.f;
    den += e0 + e1;
    acc.x = fmaf(e0, x0.x, acc.x); acc.y = fmaf(e0, x0.y, acc.y);
    acc.z = fmaf(e0, x0.z, acc.z); acc.w = fmaf(e0, x0.w, acc.w);
    acc.x = fmaf(e1, x1.x, acc.x); acc.y = fmaf(e1, x1.y, acc.y);
    acc.z = fmaf(e1, x1.z, acc.z); acc.w = fmaf(e1, x1.w, acc.w);
  }

  // reduce across the 4 edge slots
#pragma unroll
  for (int m = 16; m <= 32; m <<= 1) {
    den   += __shfl_xor(den, m);
    acc.x += __shfl_xor(acc.x, m);
    acc.y += __shfl_xor(acc.y, m);
    acc.z += __shfl_xor(acc.z, m);
    acc.w += __shfl_xor(acc.w, m);
  }

  if (g == 0) {
    float inv = (e > s) ? 1.f / den : 0.f;   // deg==0 -> zeros
    float4 b4 = *reinterpret_cast<const float4*>(bias + fo);
    float4 r;
    r.x = fmaf(acc.x, inv, b4.x);
    r.y = fmaf(acc.y, inv, b4.y);
    r.z = fmaf(acc.z, inv, b4.z);
    r.w = fmaf(acc.w, inv, b4.w);
    *reinterpret_cast<float4*>(out + (size_t)n * 64 + fo) = r;
  }
}

extern "C" void kernel_launch(void* const* d_in, const int* in_sizes, int n_in,
                              void* d_out, int out_size, void* d_ws, size_t ws_size,
                              hipStream_t stream) {
  const float* feat = (const float*)d_in[0];
  const int*   edge = (const int*)d_in[1];
  const float* wl   = (const float*)d_in[2];
  const float* wr   = (const float*)d_in[3];
  const float* att  = (const float*)d_in[4];
  const float* bias = (const float*)d_in[5];
  float* out = (float*)d_out;

  // workspace layout (~58.9 MB)
  float* h     = (float*)d_ws;                 // NN*128 f32
  int* ssrc    = (int*)(h + (size_t)NN * 128); // NE
  int* cnt     = ssrc + NE;                    // NN
  int* cursor  = cnt + NN;                     // NN
  int* start   = cursor + NN;                  // NN+1
  int* bsums   = start + NN + 1;               // 49

  (void)hipMemsetAsync(cnt, 0, 2 * NN * sizeof(int), stream);  // cnt + cursor

  gemm_dual<<<(NN + 31) / 32, 256, 0, stream>>>(feat, wl, wr, h);
  hist_k<<<(NE + 255) / 256, 256, 0, stream>>>(edge + NE, cnt);
  scan1_k<<<49, 256, 0, stream>>>(cnt, start, bsums);
  scan2_k<<<1, 64, 0, stream>>>(bsums, 49);
  scan3_k<<<(NN + 255) / 256, 256, 0, stream>>>(start, bsums);
  scatter_k<<<(NE + 255) / 256, 256, 0, stream>>>(edge, start, cursor, ssrc);
  node_k<<<NN / 4, 256, 0, stream>>>(h, ssrc, start, att, bias, out);
}

// Round 5
// 304.900 us; speedup vs baseline: 1.6082x; 1.2511x over previous
//
#include <hip/hip_runtime.h>

#define NN 100000
#define NE 1600000
#define NB 782          // ceil(NN/128) coarse buckets, 128 nodes each
#define CHUNK 8192
#define CAP 6144        // bsort LDS staging cap (bucket avg ~2046, +45 sigma safe)

#define FMA4(A_, S_, W_)                                          \
  A_.x = fmaf(S_, W_.x, A_.x); A_.y = fmaf(S_, W_.y, A_.y);       \
  A_.z = fmaf(S_, W_.z, A_.z); A_.w = fmaf(S_, W_.w, A_.w);

// h[n][0:64] = feat@W_l row, h[n][64:128] = feat@W_r row
__global__ __launch_bounds__(256) void gemm_dual(const float* __restrict__ feat,
                                                 const float* __restrict__ wl,
                                                 const float* __restrict__ wr,
                                                 float* __restrict__ h) {
  __shared__ float ldsW[128][128];   // 64 KB combined [k][c]
  __shared__ float ldsF[32][128];    // 16 KB feature tile
  const int tid = threadIdx.x;

  for (int idx = tid; idx < 2048; idx += 256) {
    int k = idx >> 4, c4 = (idx & 15) * 4;
    float4 vl = reinterpret_cast<const float4*>(wl)[idx];
    float4 vr = reinterpret_cast<const float4*>(wr)[idx];
    *reinterpret_cast<float4*>(&ldsW[k][c4])      = vl;
    *reinterpret_cast<float4*>(&ldsW[k][c4 + 64]) = vr;
  }

  const int row0 = blockIdx.x * 32;
  for (int idx = tid; idx < 32 * 32; idx += 256) {
    int r = idx >> 5, c4 = idx & 31;
    int gr = row0 + r;
    float4 v = make_float4(0.f, 0.f, 0.f, 0.f);
    if (gr < NN) v = reinterpret_cast<const float4*>(feat)[(size_t)gr * 32 + c4];
    *reinterpret_cast<float4*>(&ldsF[r][c4 * 4]) = v;
  }
  __syncthreads();

  const int r0 = (tid >> 5) * 4;
  const int c0 = (tid & 31) * 4;
  float4 acc[4];
  acc[0] = acc[1] = acc[2] = acc[3] = make_float4(0.f, 0.f, 0.f, 0.f);

  for (int k = 0; k < 128; k += 4) {
    float4 w0 = *reinterpret_cast<const float4*>(&ldsW[k    ][c0]);
    float4 w1 = *reinterpret_cast<const float4*>(&ldsW[k + 1][c0]);
    float4 w2 = *reinterpret_cast<const float4*>(&ldsW[k + 2][c0]);
    float4 w3 = *reinterpret_cast<const float4*>(&ldsW[k + 3][c0]);
#pragma unroll
    for (int i = 0; i < 4; ++i) {
      float4 f = *reinterpret_cast<const float4*>(&ldsF[r0 + i][k]);
      FMA4(acc[i], f.x, w0);
      FMA4(acc[i], f.y, w1);
      FMA4(acc[i], f.z, w2);
      FMA4(acc[i], f.w, w3);
    }
  }

#pragma unroll
  for (int i = 0; i < 4; ++i) {
    int gr = row0 + r0 + i;
    if (gr < NN)
      *reinterpret_cast<float4*>(&h[(size_t)gr * 128 + c0]) = acc[i];
  }
}

// Phase A: coarse bucket histogram (LDS pre-aggregation, few global atomics)
__global__ __launch_bounds__(256) void bhist_k(const int* __restrict__ tgt,
                                               int* __restrict__ bcnt) {
  __shared__ int lh[NB];
  const int tid = threadIdx.x;
  const int base = blockIdx.x * CHUNK;
  const int lim = min(CHUNK, NE - base);
  for (int b = tid; b < NB; b += 256) lh[b] = 0;
  __syncthreads();
  for (int i = tid; i < lim; i += 256)
    atomicAdd(&lh[tgt[base + i] >> 7], 1);
  __syncthreads();
  for (int b = tid; b < NB; b += 256)
    if (lh[b]) atomicAdd(&bcnt[b], lh[b]);
}

// Phase B: exclusive scan of bucket counts (single block)
__global__ __launch_bounds__(256) void bscan_k(const int* __restrict__ bcnt,
                                               int* __restrict__ bstart,
                                               int* __restrict__ bcursor) {
  __shared__ int sd[256];
  const int tid = threadIdx.x;
  int v[4]; int s = 0;
#pragma unroll
  for (int j = 0; j < 4; ++j) {
    int idx = tid * 4 + j;
    v[j] = (idx < NB) ? bcnt[idx] : 0;
    s += v[j];
  }
  sd[tid] = s;
  __syncthreads();
  for (int off = 1; off < 256; off <<= 1) {
    int t = (tid >= off) ? sd[tid - off] : 0;
    __syncthreads();
    sd[tid] += t;
    __syncthreads();
  }
  int run = sd[tid] - s;
#pragma unroll
  for (int j = 0; j < 4; ++j) {
    int idx = tid * 4 + j;
    if (idx < NB) { bstart[idx] = run; bcursor[idx] = run; }
    run += v[j];
  }
  if (tid == 255) bstart[NB] = NE;
}

// Phase C: bucket-partition edges; LDS-staged so global writes are
// bucket-contiguous runs (kills write amplification). rec = (src<<7)|tgt_local.
__global__ __launch_bounds__(256) void bscatter_k(const int* __restrict__ edge,
                                                  int* __restrict__ bcursor,
                                                  int* __restrict__ brec) {
  __shared__ int lcnt[NB];
  __shared__ int lstart[NB];
  __shared__ int gbase[NB];
  __shared__ int lcur[NB];
  __shared__ int srec[CHUNK];
  __shared__ int sd[256];
  const int tid = threadIdx.x;
  const int base = blockIdx.x * CHUNK;
  const int lim = min(CHUNK, NE - base);

  for (int b = tid; b < NB; b += 256) { lcnt[b] = 0; lcur[b] = 0; }
  __syncthreads();
  for (int i = tid; i < lim; i += 256)
    atomicAdd(&lcnt[edge[NE + base + i] >> 7], 1);
  __syncthreads();

  // LDS exclusive scan of lcnt -> lstart (4 elems/thread)
  int v[4]; int s = 0;
#pragma unroll
  for (int j = 0; j < 4; ++j) {
    int idx = tid * 4 + j;
    v[j] = (idx < NB) ? lcnt[idx] : 0;
    s += v[j];
  }
  sd[tid] = s;
  __syncthreads();
  for (int off = 1; off < 256; off <<= 1) {
    int t = (tid >= off) ? sd[tid - off] : 0;
    __syncthreads();
    sd[tid] += t;
    __syncthreads();
  }
  int run = sd[tid] - s;
#pragma unroll
  for (int j = 0; j < 4; ++j) {
    int idx = tid * 4 + j;
    if (idx < NB) lstart[idx] = run;
    run += v[j];
  }
  __syncthreads();

  // reserve global ranges (one atomic per nonzero bucket per block)
  for (int b = tid; b < NB; b += 256)
    if (lcnt[b] > 0) gbase[b] = atomicAdd(&bcursor[b], lcnt[b]);
  __syncthreads();

  // stage records into LDS, sorted by bucket
  for (int i = tid; i < lim; i += 256) {
    int tg = edge[NE + base + i];
    int sr = edge[base + i];
    int b = tg >> 7;
    int r = atomicAdd(&lcur[b], 1);
    srec[lstart[b] + r] = (sr << 7) | (tg & 127);
  }
  __syncthreads();

  // write out bucket-contiguous runs
  const int wid = tid >> 6, lane = tid & 63;
  for (int b = wid; b < NB; b += 4) {
    int c = lcnt[b], ls = lstart[b], gb = gbase[b];
    for (int o = lane; o < c; o += 64)
      brec[gb + o] = srec[ls + o];
  }
}

// Phase D: in-place node-level sort within each bucket (L2-resident window);
// also emits node-level start[].
__global__ __launch_bounds__(256) void bsort_k(int* __restrict__ brec,
                                               const int* __restrict__ bstart,
                                               int* __restrict__ start) {
  __shared__ int srec[CAP];
  __shared__ int ncnt[128];
  __shared__ int nst[128];
  __shared__ int sd2[128];
  const int tid = threadIdx.x;
  const int b = blockIdx.x;
  const int s0 = bstart[b];
  const int cnt = bstart[b + 1] - s0;

  if (tid < 128) ncnt[tid] = 0;
  __syncthreads();
  for (int i = tid; i < cnt; i += 256) {
    int r = brec[s0 + i];
    srec[i] = r;
    atomicAdd(&ncnt[r & 127], 1);
  }
  __syncthreads();

  // exclusive scan of ncnt[128] -> nst
  int val = (tid < 128) ? ncnt[tid] : 0;
  if (tid < 128) sd2[tid] = val;
  __syncthreads();
  for (int off = 1; off < 128; off <<= 1) {
    int t = 0;
    if (tid < 128 && tid >= off) t = sd2[tid - off];
    __syncthreads();
    if (tid < 128) sd2[tid] += t;
    __syncthreads();
  }
  if (tid < 128) {
    nst[tid] = sd2[tid] - val;
    int nid = (b << 7) + tid;
    if (nid < NN) start[nid] = s0 + nst[tid];
    ncnt[tid] = 0;                       // reuse as cursor
  }
  if (b == NB - 1 && tid == 0) start[NN] = NE;
  __syncthreads();

  for (int i = tid; i < cnt; i += 256) {
    int r = srec[i];
    int tl = r & 127;
    int p = atomicAdd(&ncnt[tl], 1);
    brec[s0 + nst[tl] + p] = r >> 7;     // final: sorted src ids
  }
}

// One wave per node; 16 lanes per edge (4 heads x float4), 8 edges in flight.
__global__ __launch_bounds__(256) void node_k(const float* __restrict__ h,
                                              const int* __restrict__ ssrc,
                                              const int* __restrict__ start,
                                              const float* __restrict__ att,
                                              const float* __restrict__ bias,
                                              float* __restrict__ out) {
  const int lane = threadIdx.x & 63;
  const int n  = blockIdx.x * 4 + (threadIdx.x >> 6);
  const int g  = lane >> 4;          // edge slot 0..3
  const int fo = (lane & 15) * 4;    // (head,feature-quad) offset within 64

  const float4 xi = *reinterpret_cast<const float4*>(h + (size_t)n * 128 + fo);
  const float4 a  = *reinterpret_cast<const float4*>(att + fo);
  const int s = start[n];
  const int e = start[n + 1];
  const float* __restrict__ hr = h + 64 + fo;

  float  den = 0.f;
  float4 acc = make_float4(0.f, 0.f, 0.f, 0.f);

  for (int i = s; i < e; i += 8) {
    int r0 = i + g, r1 = i + 4 + g;
    bool v0 = r0 < e, v1 = r1 < e;
    int j0 = ssrc[v0 ? r0 : s];
    int j1 = ssrc[v1 ? r1 : s];
    float4 x0 = *reinterpret_cast<const float4*>(hr + (size_t)j0 * 128);
    float4 x1 = *reinterpret_cast<const float4*>(hr + (size_t)j1 * 128);

    float4 z0, z1;
    z0.x = xi.x + x0.x; z0.y = xi.y + x0.y; z0.z = xi.z + x0.z; z0.w = xi.w + x0.w;
    z1.x = xi.x + x1.x; z1.y = xi.y + x1.y; z1.z = xi.z + x1.z; z1.w = xi.w + x1.w;
    z0.x = fmaxf(z0.x, 0.2f * z0.x); z0.y = fmaxf(z0.y, 0.2f * z0.y);
    z0.z = fmaxf(z0.z, 0.2f * z0.z); z0.w = fmaxf(z0.w, 0.2f * z0.w);
    z1.x = fmaxf(z1.x, 0.2f * z1.x); z1.y = fmaxf(z1.y, 0.2f * z1.y);
    z1.z = fmaxf(z1.z, 0.2f * z1.z); z1.w = fmaxf(z1.w, 0.2f * z1.w);

    float t0 = z0.x * a.x; t0 = fmaf(z0.y, a.y, t0);
    t0 = fmaf(z0.z, a.z, t0); t0 = fmaf(z0.w, a.w, t0);
    float t1 = z1.x * a.x; t1 = fmaf(z1.y, a.y, t1);
    t1 = fmaf(z1.z, a.z, t1); t1 = fmaf(z1.w, a.w, t1);

    t0 += __shfl_xor(t0, 1); t0 += __shfl_xor(t0, 2);
    t1 += __shfl_xor(t1, 1); t1 += __shfl_xor(t1, 2);

    float e0 = v0 ? __expf(t0) : 0.f;
    float e1 = v1 ? __expf(t1) : 0.f;
    den += e0 + e1;
    acc.x = fmaf(e0, x0.x, acc.x); acc.y = fmaf(e0, x0.y, acc.y);
    acc.z = fmaf(e0, x0.z, acc.z); acc.w = fmaf(e0, x0.w, acc.w);
    acc.x = fmaf(e1, x1.x, acc.x); acc.y = fmaf(e1, x1.y, acc.y);
    acc.z = fmaf(e1, x1.z, acc.z); acc.w = fmaf(e1, x1.w, acc.w);
  }

#pragma unroll
  for (int m = 16; m <= 32; m <<= 1) {
    den   += __shfl_xor(den, m);
    acc.x += __shfl_xor(acc.x, m);
    acc.y += __shfl_xor(acc.y, m);
    acc.z += __shfl_xor(acc.z, m);
    acc.w += __shfl_xor(acc.w, m);
  }

  if (g == 0) {
    float inv = (e > s) ? 1.f / den : 0.f;
    float4 b4 = *reinterpret_cast<const float4*>(bias + fo);
    float4 r;
    r.x = fmaf(acc.x, inv, b4.x);
    r.y = fmaf(acc.y, inv, b4.y);
    r.z = fmaf(acc.z, inv, b4.z);
    r.w = fmaf(acc.w, inv, b4.w);
    *reinterpret_cast<float4*>(out + (size_t)n * 64 + fo) = r;
  }
}

extern "C" void kernel_launch(void* const* d_in, const int* in_sizes, int n_in,
                              void* d_out, int out_size, void* d_ws, size_t ws_size,
                              hipStream_t stream) {
  const float* feat = (const float*)d_in[0];
  const int*   edge = (const int*)d_in[1];
  const float* wl   = (const float*)d_in[2];
  const float* wr   = (const float*)d_in[3];
  const float* att  = (const float*)d_in[4];
  const float* bias = (const float*)d_in[5];
  float* out = (float*)d_out;

  // workspace layout (~58.1 MB)
  float* h      = (float*)d_ws;                    // NN*128 f32
  int* brec     = (int*)(h + (size_t)NN * 128);    // NE (bucketed recs -> final ssrc, in-place)
  int* bcnt     = brec + NE;                       // NB
  int* bstart   = bcnt + NB;                       // NB+1
  int* bcursor  = bstart + NB + 1;                 // NB
  int* start    = bcursor + NB;                    // NN+1

  (void)hipMemsetAsync(bcnt, 0, NB * sizeof(int), stream);

  const int nchunk = (NE + CHUNK - 1) / CHUNK;     // 196
  gemm_dual<<<(NN + 31) / 32, 256, 0, stream>>>(feat, wl, wr, h);
  bhist_k<<<nchunk, 256, 0, stream>>>(edge + NE, bcnt);
  bscan_k<<<1, 256, 0, stream>>>(bcnt, bstart, bcursor);
  bscatter_k<<<nchunk, 256, 0, stream>>>(edge, bcursor, brec);
  bsort_k<<<NB, 256, 0, stream>>>(brec, bstart, start);
  node_k<<<NN / 4, 256, 0, stream>>>(h, brec, start, att, bias, out);
}

// Round 6
// 260.745 us; speedup vs baseline: 1.8805x; 1.1693x over previous
//
#include <hip/hip_runtime.h>

#define NN 100000
#define NE 1600000
#define NB 782          // ceil(NN/128) coarse buckets, 128 nodes each
#define CHUNK 8192
#define CAP 6144        // bsort LDS staging cap (bucket avg ~2046 sigma ~45)
#define LDP 136         // LDS row pitch in bf16 (128 + 8 pad -> 272B, 2-way free)

typedef __attribute__((ext_vector_type(8))) short bf16x8;
typedef __attribute__((ext_vector_type(4))) float f32x4;

static __device__ __forceinline__ unsigned short f2bf(float f) {
  unsigned int u = __float_as_uint(f);
  u += 0x7fff + ((u >> 16) & 1);       // round-to-nearest-even
  return (unsigned short)(u >> 16);
}

// One-time: wt[c][k] = bf16(W[k][c]), combined cols (c<64 -> W_l, c>=64 -> W_r)
__global__ void wprep_k(const float* __restrict__ wl, const float* __restrict__ wr,
                        unsigned short* __restrict__ wt) {
  int i = blockIdx.x * 256 + threadIdx.x;     // 16384
  int c = i >> 7, k = i & 127;
  float v = (c < 64) ? wl[k * 64 + c] : wr[k * 64 + (c - 64)];
  wt[i] = f2bf(v);
}

// MFMA bf16 GEMM: h[row][0:128] = feat[row] @ [W_l | W_r], 128-row tiles.
__global__ __launch_bounds__(256) void gemm_mfma(const float* __restrict__ feat,
                                                 const unsigned short* __restrict__ wt,
                                                 float* __restrict__ h) {
  __shared__ unsigned short ldsA[128][LDP];   // feat tile, bf16 [row][k]
  __shared__ unsigned short ldsB[128][LDP];   // weights  [col][k]
  const int tid = threadIdx.x;
  const int row0 = blockIdx.x * 128;

  // stage B (16 KB L2-resident, uint4 = 8 bf16)
  for (int idx = tid; idx < 2048; idx += 256) {
    uint4 v = reinterpret_cast<const uint4*>(wt)[idx];
    *reinterpret_cast<uint4*>(&ldsB[idx >> 4][(idx & 15) * 8]) = v;
  }

  // stage A with fp32->bf16 convert; fully coalesced (32 float4 lanes per row)
  for (int it = 0; it < 16; ++it) {
    int r = it * 8 + (tid >> 5);
    int gr = row0 + r;
    int k4 = (tid & 31) * 4;
    float4 v = make_float4(0.f, 0.f, 0.f, 0.f);
    if (gr < NN) v = *reinterpret_cast<const float4*>(&feat[(size_t)gr * 128 + k4]);
    union { unsigned short s[4]; uint2 u; } pk;
    pk.s[0] = f2bf(v.x); pk.s[1] = f2bf(v.y); pk.s[2] = f2bf(v.z); pk.s[3] = f2bf(v.w);
    *reinterpret_cast<uint2*>(&ldsA[r][k4]) = pk.u;
  }
  __syncthreads();

  const int w  = tid >> 6;          // wave 0..3 owns rows w*32..w*32+31
  const int ln = tid & 63;
  const int lr = ln & 15;
  const int kb = (ln >> 4) * 8;     // k-octet within a 32-wide K-step

  f32x4 acc[2][8];
#pragma unroll
  for (int mt = 0; mt < 2; ++mt)
#pragma unroll
    for (int nt = 0; nt < 8; ++nt) acc[mt][nt] = (f32x4){0.f, 0.f, 0.f, 0.f};

#pragma unroll
  for (int t = 0; t < 4; ++t) {
    const int ko = t * 32 + kb;
    bf16x8 af0 = *reinterpret_cast<const bf16x8*>(&ldsA[w * 32 + lr][ko]);
    bf16x8 af1 = *reinterpret_cast<const bf16x8*>(&ldsA[w * 32 + 16 + lr][ko]);
    bf16x8 bfr[8];
#pragma unroll
    for (int nt = 0; nt < 8; ++nt)
      bfr[nt] = *reinterpret_cast<const bf16x8*>(&ldsB[nt * 16 + lr][ko]);
#pragma unroll
    for (int nt = 0; nt < 8; ++nt) {
      acc[0][nt] = __builtin_amdgcn_mfma_f32_16x16x32_bf16(af0, bfr[nt], acc[0][nt], 0, 0, 0);
      acc[1][nt] = __builtin_amdgcn_mfma_f32_16x16x32_bf16(af1, bfr[nt], acc[1][nt], 0, 0, 0);
    }
  }

#pragma unroll
  for (int mt = 0; mt < 2; ++mt) {
    int rrel = w * 32 + mt * 16 + (ln >> 4) * 4;
#pragma unroll
    for (int q = 0; q < 4; ++q) {
      int gr = row0 + rrel + q;
      if (gr < NN) {
#pragma unroll
        for (int nt = 0; nt < 8; ++nt)
          h[(size_t)gr * 128 + nt * 16 + lr] = acc[mt][nt][q];
      }
    }
  }
}

// Phase A: coarse bucket histogram. Global counters padded to 1/cacheline.
__global__ __launch_bounds__(256) void bhist_k(const int* __restrict__ tgt,
                                               int* __restrict__ bcnt) {
  __shared__ int lh[NB];
  const int tid = threadIdx.x;
  const int base = blockIdx.x * CHUNK;
  const int lim = min(CHUNK, NE - base);
  for (int b = tid; b < NB; b += 256) lh[b] = 0;
  __syncthreads();
  for (int i = tid; i < lim; i += 256)
    atomicAdd(&lh[tgt[base + i] >> 7], 1);
  __syncthreads();
  for (int b = tid; b < NB; b += 256)
    if (lh[b]) atomicAdd(&bcnt[b * 16], lh[b]);
}

// Phase B: exclusive scan of bucket counts (single block)
__global__ __launch_bounds__(256) void bscan_k(const int* __restrict__ bcnt,
                                               int* __restrict__ bstart,
                                               int* __restrict__ bcursor) {
  __shared__ int sd[256];
  const int tid = threadIdx.x;
  int v[4]; int s = 0;
#pragma unroll
  for (int j = 0; j < 4; ++j) {
    int idx = tid * 4 + j;
    v[j] = (idx < NB) ? bcnt[idx * 16] : 0;
    s += v[j];
  }
  sd[tid] = s;
  __syncthreads();
  for (int off = 1; off < 256; off <<= 1) {
    int t = (tid >= off) ? sd[tid - off] : 0;
    __syncthreads();
    sd[tid] += t;
    __syncthreads();
  }
  int run = sd[tid] - s;
#pragma unroll
  for (int j = 0; j < 4; ++j) {
    int idx = tid * 4 + j;
    if (idx < NB) { bstart[idx] = run; bcursor[idx * 16] = run; }
    run += v[j];
  }
  if (tid == 255) bstart[NB] = NE;
}

// Phase C: bucket-partition edges. LDS-staged; padded global reservation
// atomics; index-parallel bucket-contiguous writeout. rec = (src<<7)|tgt_local.
__global__ __launch_bounds__(256) void bscatter_k(const int* __restrict__ edge,
                                                  int* __restrict__ bcursor,
                                                  int* __restrict__ brec) {
  __shared__ int lcnt[NB];
  __shared__ int lstart[NB];
  __shared__ int gbase[NB];
  __shared__ int lcur[NB];
  __shared__ int srec[CHUNK];
  __shared__ unsigned short bid[CHUNK];
  __shared__ int sd[256];
  const int tid = threadIdx.x;
  const int base = blockIdx.x * CHUNK;
  const int lim = min(CHUNK, NE - base);

  for (int b = tid; b < NB; b += 256) { lcnt[b] = 0; lcur[b] = 0; }
  __syncthreads();
  for (int i = tid; i < lim; i += 256)
    atomicAdd(&lcnt[edge[NE + base + i] >> 7], 1);
  __syncthreads();

  // LDS exclusive scan of lcnt -> lstart
  int v[4]; int s = 0;
#pragma unroll
  for (int j = 0; j < 4; ++j) {
    int idx = tid * 4 + j;
    v[j] = (idx < NB) ? lcnt[idx] : 0;
    s += v[j];
  }
  sd[tid] = s;
  __syncthreads();
  for (int off = 1; off < 256; off <<= 1) {
    int t = (tid >= off) ? sd[tid - off] : 0;
    __syncthreads();
    sd[tid] += t;
    __syncthreads();
  }
  int run = sd[tid] - s;
#pragma unroll
  for (int j = 0; j < 4; ++j) {
    int idx = tid * 4 + j;
    if (idx < NB) lstart[idx] = run;
    run += v[j];
  }
  __syncthreads();

  // reserve global ranges; bcursor padded to 1 counter per 64B line
  for (int b = tid; b < NB; b += 256)
    if (lcnt[b] > 0) gbase[b] = atomicAdd(&bcursor[b * 16], lcnt[b]);
  __syncthreads();

  // stage records into LDS, bucket-sorted; remember bucket id per slot
  for (int i = tid; i < lim; i += 256) {
    int tg = edge[NE + base + i];
    int sr = edge[base + i];
    int b = tg >> 7;
    int r = atomicAdd(&lcur[b], 1);
    int slot = lstart[b] + r;
    srec[slot] = (sr << 7) | (tg & 127);
    bid[slot] = (unsigned short)b;
  }
  __syncthreads();

  // index-parallel writeout: consecutive slots -> mostly-contiguous global runs
  for (int i = tid; i < lim; i += 256) {
    int b = bid[i];
    brec[gbase[b] + i - lstart[b]] = srec[i];
  }
}

// Phase D: in-place node-level sort within each bucket; emits start[].
__global__ __launch_bounds__(256) void bsort_k(int* __restrict__ brec,
                                               const int* __restrict__ bstart,
                                               int* __restrict__ start) {
  __shared__ int srec[CAP];
  __shared__ int ncnt[128];
  __shared__ int nst[128];
  __shared__ int sd2[128];
  const int tid = threadIdx.x;
  const int b = blockIdx.x;
  const int s0 = bstart[b];
  const int cnt = bstart[b + 1] - s0;

  if (tid < 128) ncnt[tid] = 0;
  __syncthreads();
  for (int i = tid; i < cnt; i += 256) {
    int r = brec[s0 + i];
    srec[i] = r;
    atomicAdd(&ncnt[r & 127], 1);
  }
  __syncthreads();

  int val = (tid < 128) ? ncnt[tid] : 0;
  if (tid < 128) sd2[tid] = val;
  __syncthreads();
  for (int off = 1; off < 128; off <<= 1) {
    int t = 0;
    if (tid < 128 && tid >= off) t = sd2[tid - off];
    __syncthreads();
    if (tid < 128) sd2[tid] += t;
    __syncthreads();
  }
  if (tid < 128) {
    nst[tid] = sd2[tid] - val;
    int nid = (b << 7) + tid;
    if (nid < NN) start[nid] = s0 + nst[tid];
    ncnt[tid] = 0;                       // reuse as cursor
  }
  if (b == NB - 1 && tid == 0) start[NN] = NE;
  __syncthreads();

  for (int i = tid; i < cnt; i += 256) {
    int r = srec[i];
    int tl = r & 127;
    int p = atomicAdd(&ncnt[tl], 1);
    brec[s0 + nst[tl] + p] = r >> 7;     // final: grouped src ids
  }
}

// One wave per node; 16 lanes per edge (4 heads x float4), 8 edges in flight.
__global__ __launch_bounds__(256) void node_k(const float* __restrict__ h,
                                              const int* __restrict__ ssrc,
                                              const int* __restrict__ start,
                                              const float* __restrict__ att,
                                              const float* __restrict__ bias,
                                              float* __restrict__ out) {
  const int lane = threadIdx.x & 63;
  const int n  = blockIdx.x * 4 + (threadIdx.x >> 6);
  const int g  = lane >> 4;          // edge slot 0..3
  const int fo = (lane & 15) * 4;    // (head,feature-quad) offset within 64

  const float4 xi = *reinterpret_cast<const float4*>(h + (size_t)n * 128 + fo);
  const float4 a  = *reinterpret_cast<const float4*>(att + fo);
  const int s = start[n];
  const int e = start[n + 1];
  const float* __restrict__ hr = h + 64 + fo;

  float  den = 0.f;
  float4 acc = make_float4(0.f, 0.f, 0.f, 0.f);

  for (int i = s; i < e; i += 8) {
    int r0 = i + g, r1 = i + 4 + g;
    bool v0 = r0 < e, v1 = r1 < e;
    int j0 = ssrc[v0 ? r0 : s];
    int j1 = ssrc[v1 ? r1 : s];
    float4 x0 = *reinterpret_cast<const float4*>(hr + (size_t)j0 * 128);
    float4 x1 = *reinterpret_cast<const float4*>(hr + (size_t)j1 * 128);

    float4 z0, z1;
    z0.x = xi.x + x0.x; z0.y = xi.y + x0.y; z0.z = xi.z + x0.z; z0.w = xi.w + x0.w;
    z1.x = xi.x + x1.x; z1.y = xi.y + x1.y; z1.z = xi.z + x1.z; z1.w = xi.w + x1.w;
    z0.x = fmaxf(z0.x, 0.2f * z0.x); z0.y = fmaxf(z0.y, 0.2f * z0.y);
    z0.z = fmaxf(z0.z, 0.2f * z0.z); z0.w = fmaxf(z0.w, 0.2f * z0.w);
    z1.x = fmaxf(z1.x, 0.2f * z1.x); z1.y = fmaxf(z1.y, 0.2f * z1.y);
    z1.z = fmaxf(z1.z, 0.2f * z1.z); z1.w = fmaxf(z1.w, 0.2f * z1.w);

    float t0 = z0.x * a.x; t0 = fmaf(z0.y, a.y, t0);
    t0 = fmaf(z0.z, a.z, t0); t0 = fmaf(z0.w, a.w, t0);
    float t1 = z1.x * a.x; t1 = fmaf(z1.y, a.y, t1);
    t1 = fmaf(z1.z, a.z, t1); t1 = fmaf(z1.w, a.w, t1);

    t0 += __shfl_xor(t0, 1); t0 += __shfl_xor(t0, 2);
    t1 += __shfl_xor(t1, 1); t1 += __shfl_xor(t1, 2);

    float e0 = v0 ? __expf(t0) : 0.f;
    float e1 = v1 ? __expf(t1) : 0.f;
    den += e0 + e1;
    acc.x = fmaf(e0, x0.x, acc.x); acc.y = fmaf(e0, x0.y, acc.y);
    acc.z = fmaf(e0, x0.z, acc.z); acc.w = fmaf(e0, x0.w, acc.w);
    acc.x = fmaf(e1, x1.x, acc.x); acc.y = fmaf(e1, x1.y, acc.y);
    acc.z = fmaf(e1, x1.z, acc.z); acc.w = fmaf(e1, x1.w, acc.w);
  }

#pragma unroll
  for (int m = 16; m <= 32; m <<= 1) {
    den   += __shfl_xor(den, m);
    acc.x += __shfl_xor(acc.x, m);
    acc.y += __shfl_xor(acc.y, m);
    acc.z += __shfl_xor(acc.z, m);
    acc.w += __shfl_xor(acc.w, m);
  }

  if (g == 0) {
    float inv = (e > s) ? 1.f / den : 0.f;
    float4 b4 = *reinterpret_cast<const float4*>(bias + fo);
    float4 r;
    r.x = fmaf(acc.x, inv, b4.x);
    r.y = fmaf(acc.y, inv, b4.y);
    r.z = fmaf(acc.z, inv, b4.z);
    r.w = fmaf(acc.w, inv, b4.w);
    *reinterpret_cast<float4*>(out + (size_t)n * 64 + fo) = r;
  }
}

extern "C" void kernel_launch(void* const* d_in, const int* in_sizes, int n_in,
                              void* d_out, int out_size, void* d_ws, size_t ws_size,
                              hipStream_t stream) {
  const float* feat = (const float*)d_in[0];
  const int*   edge = (const int*)d_in[1];
  const float* wl   = (const float*)d_in[2];
  const float* wr   = (const float*)d_in[3];
  const float* att  = (const float*)d_in[4];
  const float* bias = (const float*)d_in[5];
  float* out = (float*)d_out;

  // workspace layout (~58.2 MB)
  float* h        = (float*)d_ws;                  // NN*128 f32
  int*   brec     = (int*)(h + (size_t)NN * 128);  // NE
  int*   bcnt     = brec + NE;                     // NB*16 (padded, 1/line)
  int*   bstart   = bcnt + NB * 16;                // NB+1
  int*   bcursor  = bstart + NB + 1;               // NB*16 (padded)
  int*   start    = bcursor + NB * 16;             // NN+1
  unsigned short* wt = (unsigned short*)(start + NN + 1);  // 16384 bf16

  (void)hipMemsetAsync(bcnt, 0, NB * 16 * sizeof(int), stream);

  const int nchunk = (NE + CHUNK - 1) / CHUNK;     // 196
  wprep_k<<<64, 256, 0, stream>>>(wl, wr, wt);
  gemm_mfma<<<(NN + 127) / 128, 256, 0, stream>>>(feat, wt, h);
  bhist_k<<<nchunk, 256, 0, stream>>>(edge + NE, bcnt);
  bscan_k<<<1, 256, 0, stream>>>(bcnt, bstart, bcursor);
  bscatter_k<<<nchunk, 256, 0, stream>>>(edge, bcursor, brec);
  bsort_k<<<NB, 256, 0, stream>>>(brec, bstart, start);
  node_k<<<NN / 4, 256, 0, stream>>>(h, brec, start, att, bias, out);
}

// Round 7
// 247.566 us; speedup vs baseline: 1.9806x; 1.0532x over previous
//
#include <hip/hip_runtime.h>

#define NN 100000
#define NE 1600000
#define NB 782          // ceil(NN/128) coarse buckets, 128 nodes each
#define CHUNK 8192
#define CAP 6144        // bsort LDS staging cap (bucket avg ~2046 sigma ~45)
#define LDP 136         // LDS row pitch in bf16 (128 + 8 pad -> 272B, 2-way free)

typedef __attribute__((ext_vector_type(8))) short bf16x8;
typedef __attribute__((ext_vector_type(4))) float f32x4;

static __device__ __forceinline__ unsigned short f2bf(float f) {
  unsigned int u = __float_as_uint(f);
  u += 0x7fff + ((u >> 16) & 1);       // round-to-nearest-even
  return (unsigned short)(u >> 16);
}

// One-time: wt[c][k] = bf16(W[k][c]), combined cols (c<64 -> W_l, c>=64 -> W_r)
__global__ void wprep_k(const float* __restrict__ wl, const float* __restrict__ wr,
                        unsigned short* __restrict__ wt) {
  int i = blockIdx.x * 256 + threadIdx.x;     // 16384
  int c = i >> 7, k = i & 127;
  float v = (c < 64) ? wl[k * 64 + c] : wr[k * 64 + (c - 64)];
  wt[i] = f2bf(v);
}

// MFMA bf16 GEMM, 128-row tiles: hl[row][0:64] f32, hrb[row][0:64] bf16.
__global__ __launch_bounds__(256) void gemm_mfma(const float* __restrict__ feat,
                                                 const unsigned short* __restrict__ wt,
                                                 float* __restrict__ hl,
                                                 unsigned short* __restrict__ hrb) {
  __shared__ unsigned short ldsA[128][LDP];   // feat tile, bf16 [row][k]
  __shared__ unsigned short ldsB[128][LDP];   // weights  [col][k]
  const int tid = threadIdx.x;
  const int row0 = blockIdx.x * 128;

  // stage B (16 KB L2-resident, uint4 = 8 bf16)
  for (int idx = tid; idx < 2048; idx += 256) {
    uint4 v = reinterpret_cast<const uint4*>(wt)[idx];
    *reinterpret_cast<uint4*>(&ldsB[idx >> 4][(idx & 15) * 8]) = v;
  }

  // stage A with fp32->bf16 convert; fully coalesced (32 float4 lanes per row)
  for (int it = 0; it < 16; ++it) {
    int r = it * 8 + (tid >> 5);
    int gr = row0 + r;
    int k4 = (tid & 31) * 4;
    float4 v = make_float4(0.f, 0.f, 0.f, 0.f);
    if (gr < NN) v = *reinterpret_cast<const float4*>(&feat[(size_t)gr * 128 + k4]);
    union { unsigned short s[4]; uint2 u; } pk;
    pk.s[0] = f2bf(v.x); pk.s[1] = f2bf(v.y); pk.s[2] = f2bf(v.z); pk.s[3] = f2bf(v.w);
    *reinterpret_cast<uint2*>(&ldsA[r][k4]) = pk.u;
  }
  __syncthreads();

  const int w  = tid >> 6;          // wave 0..3 owns rows w*32..w*32+31
  const int ln = tid & 63;
  const int lr = ln & 15;
  const int kb = (ln >> 4) * 8;     // k-octet within a 32-wide K-step

  f32x4 acc[2][8];
#pragma unroll
  for (int mt = 0; mt < 2; ++mt)
#pragma unroll
    for (int nt = 0; nt < 8; ++nt) acc[mt][nt] = (f32x4){0.f, 0.f, 0.f, 0.f};

#pragma unroll
  for (int t = 0; t < 4; ++t) {
    const int ko = t * 32 + kb;
    bf16x8 af0 = *reinterpret_cast<const bf16x8*>(&ldsA[w * 32 + lr][ko]);
    bf16x8 af1 = *reinterpret_cast<const bf16x8*>(&ldsA[w * 32 + 16 + lr][ko]);
    bf16x8 bfr[8];
#pragma unroll
    for (int nt = 0; nt < 8; ++nt)
      bfr[nt] = *reinterpret_cast<const bf16x8*>(&ldsB[nt * 16 + lr][ko]);
#pragma unroll
    for (int nt = 0; nt < 8; ++nt) {
      acc[0][nt] = __builtin_amdgcn_mfma_f32_16x16x32_bf16(af0, bfr[nt], acc[0][nt], 0, 0, 0);
      acc[1][nt] = __builtin_amdgcn_mfma_f32_16x16x32_bf16(af1, bfr[nt], acc[1][nt], 0, 0, 0);
    }
  }

#pragma unroll
  for (int mt = 0; mt < 2; ++mt) {
    int rrel = w * 32 + mt * 16 + (ln >> 4) * 4;
#pragma unroll
    for (int q = 0; q < 4; ++q) {
      int gr = row0 + rrel + q;
      if (gr < NN) {
#pragma unroll
        for (int nt = 0; nt < 4; ++nt)       // cols 0..63 -> h_l (f32)
          hl[(size_t)gr * 64 + nt * 16 + lr] = acc[mt][nt][q];
#pragma unroll
        for (int nt = 4; nt < 8; ++nt)       // cols 64..127 -> h_r (bf16)
          hrb[(size_t)gr * 64 + (nt - 4) * 16 + lr] = f2bf(acc[mt][nt][q]);
      }
    }
  }
}

// Phase A: coarse bucket histogram. Global counters padded to 1/cacheline.
__global__ __launch_bounds__(256) void bhist_k(const int* __restrict__ tgt,
                                               int* __restrict__ bcnt) {
  __shared__ int lh[NB];
  const int tid = threadIdx.x;
  const int base = blockIdx.x * CHUNK;
  const int lim = min(CHUNK, NE - base);
  for (int b = tid; b < NB; b += 256) lh[b] = 0;
  __syncthreads();
  for (int i = tid; i < lim; i += 256)
    atomicAdd(&lh[tgt[base + i] >> 7], 1);
  __syncthreads();
  for (int b = tid; b < NB; b += 256)
    if (lh[b]) atomicAdd(&bcnt[b * 16], lh[b]);
}

// Phase B: exclusive scan of bucket counts (single block)
__global__ __launch_bounds__(256) void bscan_k(const int* __restrict__ bcnt,
                                               int* __restrict__ bstart,
                                               int* __restrict__ bcursor) {
  __shared__ int sd[256];
  const int tid = threadIdx.x;
  int v[4]; int s = 0;
#pragma unroll
  for (int j = 0; j < 4; ++j) {
    int idx = tid * 4 + j;
    v[j] = (idx < NB) ? bcnt[idx * 16] : 0;
    s += v[j];
  }
  sd[tid] = s;
  __syncthreads();
  for (int off = 1; off < 256; off <<= 1) {
    int t = (tid >= off) ? sd[tid - off] : 0;
    __syncthreads();
    sd[tid] += t;
    __syncthreads();
  }
  int run = sd[tid] - s;
#pragma unroll
  for (int j = 0; j < 4; ++j) {
    int idx = tid * 4 + j;
    if (idx < NB) { bstart[idx] = run; bcursor[idx * 16] = run; }
    run += v[j];
  }
  if (tid == 255) bstart[NB] = NE;
}

// Phase C: bucket-partition edges. LDS-staged; padded reservation atomics;
// index-parallel bucket-contiguous writeout. rec = (src<<7)|tgt_local.
__global__ __launch_bounds__(256) void bscatter_k(const int* __restrict__ edge,
                                                  int* __restrict__ bcursor,
                                                  int* __restrict__ brec) {
  __shared__ int lcnt[NB];
  __shared__ int lstart[NB];
  __shared__ int gbase[NB];
  __shared__ int lcur[NB];
  __shared__ int srec[CHUNK];
  __shared__ unsigned short bid[CHUNK];
  __shared__ int sd[256];
  const int tid = threadIdx.x;
  const int base = blockIdx.x * CHUNK;
  const int lim = min(CHUNK, NE - base);

  for (int b = tid; b < NB; b += 256) { lcnt[b] = 0; lcur[b] = 0; }
  __syncthreads();
  for (int i = tid; i < lim; i += 256)
    atomicAdd(&lcnt[edge[NE + base + i] >> 7], 1);
  __syncthreads();

  int v[4]; int s = 0;
#pragma unroll
  for (int j = 0; j < 4; ++j) {
    int idx = tid * 4 + j;
    v[j] = (idx < NB) ? lcnt[idx] : 0;
    s += v[j];
  }
  sd[tid] = s;
  __syncthreads();
  for (int off = 1; off < 256; off <<= 1) {
    int t = (tid >= off) ? sd[tid - off] : 0;
    __syncthreads();
    sd[tid] += t;
    __syncthreads();
  }
  int run = sd[tid] - s;
#pragma unroll
  for (int j = 0; j < 4; ++j) {
    int idx = tid * 4 + j;
    if (idx < NB) lstart[idx] = run;
    run += v[j];
  }
  __syncthreads();

  for (int b = tid; b < NB; b += 256)
    if (lcnt[b] > 0) gbase[b] = atomicAdd(&bcursor[b * 16], lcnt[b]);
  __syncthreads();

  for (int i = tid; i < lim; i += 256) {
    int tg = edge[NE + base + i];
    int sr = edge[base + i];
    int b = tg >> 7;
    int r = atomicAdd(&lcur[b], 1);
    int slot = lstart[b] + r;
    srec[slot] = (sr << 7) | (tg & 127);
    bid[slot] = (unsigned short)b;
  }
  __syncthreads();

  for (int i = tid; i < lim; i += 256) {
    int b = bid[i];
    brec[gbase[b] + i - lstart[b]] = srec[i];
  }
}

// Phase D: in-place node-level sort within each bucket; emits start[].
__global__ __launch_bounds__(256) void bsort_k(int* __restrict__ brec,
                                               const int* __restrict__ bstart,
                                               int* __restrict__ start) {
  __shared__ int srec[CAP];
  __shared__ int ncnt[128];
  __shared__ int nst[128];
  __shared__ int sd2[128];
  const int tid = threadIdx.x;
  const int b = blockIdx.x;
  const int s0 = bstart[b];
  const int cnt = bstart[b + 1] - s0;

  if (tid < 128) ncnt[tid] = 0;
  __syncthreads();
  for (int i = tid; i < cnt; i += 256) {
    int r = brec[s0 + i];
    srec[i] = r;
    atomicAdd(&ncnt[r & 127], 1);
  }
  __syncthreads();

  int val = (tid < 128) ? ncnt[tid] : 0;
  if (tid < 128) sd2[tid] = val;
  __syncthreads();
  for (int off = 1; off < 128; off <<= 1) {
    int t = 0;
    if (tid < 128 && tid >= off) t = sd2[tid - off];
    __syncthreads();
    if (tid < 128) sd2[tid] += t;
    __syncthreads();
  }
  if (tid < 128) {
    nst[tid] = sd2[tid] - val;
    int nid = (b << 7) + tid;
    if (nid < NN) start[nid] = s0 + nst[tid];
    ncnt[tid] = 0;                       // reuse as cursor
  }
  if (b == NB - 1 && tid == 0) start[NN] = NE;
  __syncthreads();

  for (int i = tid; i < cnt; i += 256) {
    int r = srec[i];
    int tl = r & 127;
    int p = atomicAdd(&ncnt[tl], 1);
    brec[s0 + nst[tl] + p] = r >> 7;     // final: grouped src ids
  }
}

// One wave per node; 16 lanes per edge (4 heads x float4), 8 edges in flight.
// h_r gathered as bf16 (8B/lane, 128B/edge).
__global__ __launch_bounds__(256) void node_k(const float* __restrict__ hl,
                                              const unsigned short* __restrict__ hrb,
                                              const int* __restrict__ ssrc,
                                              const int* __restrict__ start,
                                              const float* __restrict__ att,
                                              const float* __restrict__ bias,
                                              float* __restrict__ out) {
  const int lane = threadIdx.x & 63;
  const int n  = blockIdx.x * 4 + (threadIdx.x >> 6);
  const int g  = lane >> 4;          // edge slot 0..3
  const int fo = (lane & 15) * 4;    // (head,feature-quad) offset within 64

  const float4 xi = *reinterpret_cast<const float4*>(hl + (size_t)n * 64 + fo);
  const float4 a  = *reinterpret_cast<const float4*>(att + fo);
  const int s = start[n];
  const int e = start[n + 1];
  const unsigned short* __restrict__ hrp = hrb + fo;

  float  den = 0.f;
  float4 acc = make_float4(0.f, 0.f, 0.f, 0.f);

  for (int i = s; i < e; i += 8) {
    int r0 = i + g, r1 = i + 4 + g;
    bool v0 = r0 < e, v1 = r1 < e;
    int j0 = ssrc[v0 ? r0 : s];
    int j1 = ssrc[v1 ? r1 : s];
    uint2 p0 = *reinterpret_cast<const uint2*>(hrp + (size_t)j0 * 64);
    uint2 p1 = *reinterpret_cast<const uint2*>(hrp + (size_t)j1 * 64);
    float4 x0, x1;
    x0.x = __uint_as_float(p0.x << 16);
    x0.y = __uint_as_float(p0.x & 0xffff0000u);
    x0.z = __uint_as_float(p0.y << 16);
    x0.w = __uint_as_float(p0.y & 0xffff0000u);
    x1.x = __uint_as_float(p1.x << 16);
    x1.y = __uint_as_float(p1.x & 0xffff0000u);
    x1.z = __uint_as_float(p1.y << 16);
    x1.w = __uint_as_float(p1.y & 0xffff0000u);

    float4 z0, z1;
    z0.x = xi.x + x0.x; z0.y = xi.y + x0.y; z0.z = xi.z + x0.z; z0.w = xi.w + x0.w;
    z1.x = xi.x + x1.x; z1.y = xi.y + x1.y; z1.z = xi.z + x1.z; z1.w = xi.w + x1.w;
    z0.x = fmaxf(z0.x, 0.2f * z0.x); z0.y = fmaxf(z0.y, 0.2f * z0.y);
    z0.z = fmaxf(z0.z, 0.2f * z0.z); z0.w = fmaxf(z0.w, 0.2f * z0.w);
    z1.x = fmaxf(z1.x, 0.2f * z1.x); z1.y = fmaxf(z1.y, 0.2f * z1.y);
    z1.z = fmaxf(z1.z, 0.2f * z1.z); z1.w = fmaxf(z1.w, 0.2f * z1.w);

    float t0 = z0.x * a.x; t0 = fmaf(z0.y, a.y, t0);
    t0 = fmaf(z0.z, a.z, t0); t0 = fmaf(z0.w, a.w, t0);
    float t1 = z1.x * a.x; t1 = fmaf(z1.y, a.y, t1);
    t1 = fmaf(z1.z, a.z, t1); t1 = fmaf(z1.w, a.w, t1);

    t0 += __shfl_xor(t0, 1); t0 += __shfl_xor(t0, 2);
    t1 += __shfl_xor(t1, 1); t1 += __shfl_xor(t1, 2);

    float e0 = v0 ? __expf(t0) : 0.f;
    float e1 = v1 ? __expf(t1) : 0.f;
    den += e0 + e1;
    acc.x = fmaf(e0, x0.x, acc.x); acc.y = fmaf(e0, x0.y, acc.y);
    acc.z = fmaf(e0, x0.z, acc.z); acc.w = fmaf(e0, x0.w, acc.w);
    acc.x = fmaf(e1, x1.x, acc.x); acc.y = fmaf(e1, x1.y, acc.y);
    acc.z = fmaf(e1, x1.z, acc.z); acc.w = fmaf(e1, x1.w, acc.w);
  }

#pragma unroll
  for (int m = 16; m <= 32; m <<= 1) {
    den   += __shfl_xor(den, m);
    acc.x += __shfl_xor(acc.x, m);
    acc.y += __shfl_xor(acc.y, m);
    acc.z += __shfl_xor(acc.z, m);
    acc.w += __shfl_xor(acc.w, m);
  }

  if (g == 0) {
    float inv = (e > s) ? 1.f / den : 0.f;
    float4 b4 = *reinterpret_cast<const float4*>(bias + fo);
    float4 r;
    r.x = fmaf(acc.x, inv, b4.x);
    r.y = fmaf(acc.y, inv, b4.y);
    r.z = fmaf(acc.z, inv, b4.z);
    r.w = fmaf(acc.w, inv, b4.w);
    *reinterpret_cast<float4*>(out + (size_t)n * 64 + fo) = r;
  }
}

extern "C" void kernel_launch(void* const* d_in, const int* in_sizes, int n_in,
                              void* d_out, int out_size, void* d_ws, size_t ws_size,
                              hipStream_t stream) {
  const float* feat = (const float*)d_in[0];
  const int*   edge = (const int*)d_in[1];
  const float* wl   = (const float*)d_in[2];
  const float* wr   = (const float*)d_in[3];
  const float* att  = (const float*)d_in[4];
  const float* bias = (const float*)d_in[5];
  float* out = (float*)d_out;

  // workspace layout (~45.6 MB)
  float* hl       = (float*)d_ws;                        // NN*64 f32
  unsigned short* hrb = (unsigned short*)(hl + (size_t)NN * 64);  // NN*64 bf16
  int*   brec     = (int*)(hrb + (size_t)NN * 64);       // NE
  int*   bcnt     = brec + NE;                           // NB*16 (padded, 1/line)
  int*   bstart   = bcnt + NB * 16;                      // NB+1
  int*   bcursor  = bstart + NB + 1;                     // NB*16 (padded)
  int*   start    = bcursor + NB * 16;                   // NN+1
  unsigned short* wt = (unsigned short*)(start + NN + 1);  // 16384 bf16

  (void)hipMemsetAsync(bcnt, 0, NB * 16 * sizeof(int), stream);

  const int nchunk = (NE + CHUNK - 1) / CHUNK;           // 196
  wprep_k<<<64, 256, 0, stream>>>(wl, wr, wt);
  gemm_mfma<<<(NN + 127) / 128, 256, 0, stream>>>(feat, wt, hl, hrb);
  bhist_k<<<nchunk, 256, 0, stream>>>(edge + NE, bcnt);
  bscan_k<<<1, 256, 0, stream>>>(bcnt, bstart, bcursor);
  bscatter_k<<<nchunk, 256, 0, stream>>>(edge, bcursor, brec);
  bsort_k<<<NB, 256, 0, stream>>>(brec, bstart, start);
  node_k<<<NN / 4, 256, 0, stream>>>(hl, hrb, brec, start, att, bias, out);
}